// Round 8
// baseline (736.372 us; speedup 1.0000x reference)
//
#include <hip/hip_runtime.h>
#include <hip/hip_bf16.h>

// GraphSAGE R13: column-sharded aggregation for L2 residency.
//  R10's fused gather streams the whole 25.6MB gn table through each XCD's
//  4MB L2 (FETCH ~= 8x25.6MB = compulsory floor of that dataflow). Split:
//   agg_act:  shard s = blockIdx%8 (XCD round-robin heuristic; correctness
//             independent). gn stored SHARDED gnS[s][node][16] (32B slices)
//             -> per-XCD gather set 3.2MB < 4MB L2 -> gathers become L2 hits.
//             Computes h = relu(gs + mean) for its 16 cols IN-PLACE into gs
//             (own slice only -> race-free; gs doubles as h buffer).
//   gemm_mid: R10 MFMA kernel, A-phase = streaming read of h (f32->split
//             bf16 at LDS write). Epilogue: gs in-place (stage-then-write,
//             own rows) + gn sharded for next layer.
//  agg_out sharded too (gn4S shard = 1.6MB). Numerics bit-identical (same
//  j-order f32 accumulation). Workspace shrinks to ~103MB.

constexpr int N_NODES = 100000;
constexpr int FANOUT  = 16;

typedef __attribute__((ext_vector_type(8))) short short8;
typedef __attribute__((ext_vector_type(4))) float f32x4;

__device__ inline unsigned short bf16_rne(float f) {
    unsigned u = __float_as_uint(f);
    return (unsigned short)((u + 0x7fffu + ((u >> 16) & 1u)) >> 16);
}
__device__ inline float bf16_tof(unsigned short s) {
    return __uint_as_float(((unsigned)s) << 16);
}

// ---- weights -> hi/lo bf16, FRAGMENT-SWIZZLED layout ----
// off(c,k) = ((tk*(C/16)+tc)*64 + qk*16 + mlc)*8 + e
__global__ __launch_bounds__(256)
void prep_Bsw(const float* __restrict__ W, unsigned short* __restrict__ Bhi,
              unsigned short* __restrict__ Blo, int D_IN, int D_OUT)
{
    int i = blockIdx.x * 256 + threadIdx.x;
    int total = 2 * D_OUT * D_IN;
    if (i >= total) return;
    int K = D_IN, C = 2 * D_OUT;
    int c = i / K, k = i % K;
    float v = (c < D_OUT) ? W[(size_t)c * (2 * K) + k]
                          : W[(size_t)(c - D_OUT) * (2 * K) + K + k];
    int tc = c >> 4, mlc = c & 15;
    int tk = k >> 5, qk = (k >> 3) & 3, e = k & 7;
    size_t off = ((size_t)(tk * (C / 16) + tc) * 64 + qk * 16 + mlc) * 8 + e;
    unsigned short hi = bf16_rne(v);
    Bhi[off] = hi;
    Blo[off] = bf16_rne(v - bf16_tof(hi));
}

// ---- gemm1: dense, K=256, C=256. block = 32 nodes (R11 tile). ----
// Epilogue: gs full rows (stride 128) + gn SHARDED (16-col shards).
__global__ __launch_bounds__(256, 6)
void gemm1(const float* __restrict__ hf,
           const unsigned short* __restrict__ Bhi,
           const unsigned short* __restrict__ Blo,
           float* __restrict__ gs, unsigned short* __restrict__ gnS, int N)
{
    constexpr int K = 256, DO = 128, LDA = 40;
    __shared__ unsigned short Ah[32 * LDA], Al[32 * LDA];

    const int tid  = threadIdx.x;
    const int wave = tid >> 6;
    const int lane = tid & 63;
    const int ml   = lane & 15;
    const int quad = lane >> 4;
    const int node0 = blockIdx.x * 32;

    const int srow = tid >> 3;
    const int sc4  = tid & 7;
    int nd = node0 + srow; if (nd >= N) nd = N - 1;
    const float* pA = &hf[(size_t)nd * K + sc4 * 4];

    f32x4 acc[2][4];
    #pragma unroll
    for (int mi = 0; mi < 2; ++mi)
        #pragma unroll
        for (int ni = 0; ni < 4; ++ni)
            acc[mi][ni] = (f32x4){0.f, 0.f, 0.f, 0.f};

    float4 pf = *(const float4*)&pA[0];

    for (int k0 = 0; k0 < K; k0 += 32) {
        {
            float vv[4] = {pf.x, pf.y, pf.z, pf.w};
            unsigned short hi[4], lo[4];
            #pragma unroll
            for (int e = 0; e < 4; ++e) {
                hi[e] = bf16_rne(vv[e]);
                lo[e] = bf16_rne(vv[e] - bf16_tof(hi[e]));
            }
            *(uint2*)&Ah[srow * LDA + sc4 * 4] = *(const uint2*)hi;
            *(uint2*)&Al[srow * LDA + sc4 * 4] = *(const uint2*)lo;
        }
        if (k0 + 32 < K) pf = *(const float4*)&pA[k0 + 32];
        __syncthreads();

        short8 afh[2], afl[2];
        #pragma unroll
        for (int mi = 0; mi < 2; ++mi) {
            int r = mi * 16 + ml;
            afh[mi] = *(const short8*)&Ah[r * LDA + quad * 8];
            afl[mi] = *(const short8*)&Al[r * LDA + quad * 8];
        }
        const size_t bbase = (size_t)((k0 >> 5) * 16 + wave * 4) * 512 + (size_t)lane * 8;
        #pragma unroll
        for (int ni = 0; ni < 4; ++ni) {
            short8 bh = *(const short8*)&Bhi[bbase + ni * 512];
            short8 bl = *(const short8*)&Blo[bbase + ni * 512];
            #pragma unroll
            for (int mi = 0; mi < 2; ++mi) {
                acc[mi][ni] = __builtin_amdgcn_mfma_f32_16x16x32_bf16(afl[mi], bh, acc[mi][ni], 0, 0, 0);
                acc[mi][ni] = __builtin_amdgcn_mfma_f32_16x16x32_bf16(afh[mi], bl, acc[mi][ni], 0, 0, 0);
                acc[mi][ni] = __builtin_amdgcn_mfma_f32_16x16x32_bf16(afh[mi], bh, acc[mi][ni], 0, 0, 0);
            }
        }
        __syncthreads();
    }

    #pragma unroll
    for (int mi = 0; mi < 2; ++mi)
        #pragma unroll
        for (int r = 0; r < 4; ++r) {
            int node = node0 + mi * 16 + quad * 4 + r;
            if (node >= N) continue;
            #pragma unroll
            for (int ni = 0; ni < 4; ++ni) {
                int c = wave * 64 + ni * 16 + ml;
                float v = acc[mi][ni][r];
                if (c < DO) gs[(size_t)node * 128 + c] = v;
                else {
                    int cs = c - DO;
                    gnS[((size_t)(cs >> 4) * N + node) * 16 + (cs & 15)] = bf16_rne(v);
                }
            }
        }
}

// ---- agg_act: sharded gather + activation, in-place into gs ----
// shard s = blockIdx%8 (XCD heuristic); thread = node; 16 cols [16s,16s+16).
__global__ __launch_bounds__(256, 4)
void agg_act(const unsigned short* __restrict__ gnS,
             const int* __restrict__ neigh,
             float* __restrict__ gs, int N)
{
    const int s = blockIdx.x & 7;
    const int n = (blockIdx.x >> 3) * 256 + threadIdx.x;
    if (n >= N) return;
    const int4* nb4 = (const int4*)(neigh + (size_t)n * FANOUT);
    int4 q0 = nb4[0], q1 = nb4[1], q2 = nb4[2], q3 = nb4[3];
    int ids[FANOUT] = {q0.x, q0.y, q0.z, q0.w, q1.x, q1.y, q1.z, q1.w,
                       q2.x, q2.y, q2.z, q2.w, q3.x, q3.y, q3.z, q3.w};
    const unsigned short* base = gnS + (size_t)s * N * 16;
    float acc[16];
    #pragma unroll
    for (int c = 0; c < 16; ++c) acc[c] = 0.f;
    #pragma unroll
    for (int j = 0; j < FANOUT; ++j) {
        const uint4* p = (const uint4*)(base + (size_t)ids[j] * 16);
        uint4 a = p[0], b = p[1];
        acc[0]  += __uint_as_float(a.x << 16);
        acc[1]  += __uint_as_float(a.x & 0xffff0000u);
        acc[2]  += __uint_as_float(a.y << 16);
        acc[3]  += __uint_as_float(a.y & 0xffff0000u);
        acc[4]  += __uint_as_float(a.z << 16);
        acc[5]  += __uint_as_float(a.z & 0xffff0000u);
        acc[6]  += __uint_as_float(a.w << 16);
        acc[7]  += __uint_as_float(a.w & 0xffff0000u);
        acc[8]  += __uint_as_float(b.x << 16);
        acc[9]  += __uint_as_float(b.x & 0xffff0000u);
        acc[10] += __uint_as_float(b.y << 16);
        acc[11] += __uint_as_float(b.y & 0xffff0000u);
        acc[12] += __uint_as_float(b.z << 16);
        acc[13] += __uint_as_float(b.z & 0xffff0000u);
        acc[14] += __uint_as_float(b.w << 16);
        acc[15] += __uint_as_float(b.w & 0xffff0000u);
    }
    const float inv = 1.0f / (float)FANOUT;
    float* gp = gs + (size_t)n * 128 + s * 16;
    #pragma unroll
    for (int t = 0; t < 4; ++t) {
        float4 g = *(const float4*)(gp + 4 * t);
        g.x = fmaxf(fmaf(acc[4 * t + 0], inv, g.x), 0.f);
        g.y = fmaxf(fmaf(acc[4 * t + 1], inv, g.y), 0.f);
        g.z = fmaxf(fmaf(acc[4 * t + 2], inv, g.z), 0.f);
        g.w = fmaxf(fmaf(acc[4 * t + 3], inv, g.w), 0.f);
        *(float4*)(gp + 4 * t) = g;
    }
}

// ---- gemm_mid: h (f32, in gs) @ B^T. A staged f32->split-bf16. ----
// C=256 (DO=128, NI=4, gn sharded 16-col) or C=128 (DO=64, NI=2, 8-col).
// gs written in-place (stage-then-write, own rows only).
template<int C>
__global__ __launch_bounds__(256, 5)
void gemm_mid(const float* __restrict__ hbuf,
              const unsigned short* __restrict__ Bhi,
              const unsigned short* __restrict__ Blo,
              float* __restrict__ gs_out,
              unsigned short* __restrict__ gnS_out, int N)
{
    constexpr int K = 128, DO = C / 2, NI = C / 64;
    __shared__ unsigned short Afh[32 * 128], Afl[32 * 128];   // 16384 B

    const int tid  = threadIdx.x;
    const int wave = tid >> 6;
    const int lane = tid & 63;
    const int ml   = lane & 15;
    const int quad = lane >> 4;
    const int node0 = blockIdx.x * 32;

    // stage A: thread (row, sseg) reads 16 f32 (64B) of h, splits hi/lo
    {
        const int row  = tid >> 3;
        const int sseg = tid & 7;
        int nd = node0 + row; if (nd >= N) nd = N - 1;
        const float* hp = &hbuf[(size_t)nd * 128 + sseg * 16];
        #pragma unroll
        for (int cc = 0; cc < 2; ++cc) {
            float4 v0 = *(const float4*)(hp + 8 * cc);
            float4 v1 = *(const float4*)(hp + 8 * cc + 4);
            float sv[8] = {v0.x, v0.y, v0.z, v0.w, v1.x, v1.y, v1.z, v1.w};
            alignas(16) unsigned short th[8], tl[8];
            #pragma unroll
            for (int e = 0; e < 8; ++e) {
                unsigned short hi = bf16_rne(sv[e]);
                th[e] = hi;
                tl[e] = bf16_rne(sv[e] - bf16_tof(hi));
            }
            int soff = (row * 128 + sseg * 16 + 8 * cc) ^ ((row & 7) << 3);
            *(uint4*)&Afh[soff] = *(const uint4*)th;
            *(uint4*)&Afl[soff] = *(const uint4*)tl;
        }
    }
    __syncthreads();

    f32x4 acc[2][NI];
    #pragma unroll
    for (int mi = 0; mi < 2; ++mi)
        #pragma unroll
        for (int ni = 0; ni < NI; ++ni)
            acc[mi][ni] = (f32x4){0.f, 0.f, 0.f, 0.f};

    for (int k0 = 0; k0 < K; k0 += 32) {
        short8 afh[2], afl[2];
        #pragma unroll
        for (int mi = 0; mi < 2; ++mi) {
            int r = mi * 16 + ml;
            int soff = (r * 128 + k0 + quad * 8) ^ ((r & 7) << 3);
            afh[mi] = *(const short8*)&Afh[soff];
            afl[mi] = *(const short8*)&Afl[soff];
        }
        const size_t bbase = (size_t)((k0 >> 5) * (C / 16) + wave * NI) * 512 + (size_t)lane * 8;
        #pragma unroll
        for (int ni = 0; ni < NI; ++ni) {
            short8 bh = *(const short8*)&Bhi[bbase + ni * 512];
            short8 bl = *(const short8*)&Blo[bbase + ni * 512];
            #pragma unroll
            for (int mi = 0; mi < 2; ++mi) {
                acc[mi][ni] = __builtin_amdgcn_mfma_f32_16x16x32_bf16(afl[mi], bh, acc[mi][ni], 0, 0, 0);
                acc[mi][ni] = __builtin_amdgcn_mfma_f32_16x16x32_bf16(afh[mi], bl, acc[mi][ni], 0, 0, 0);
                acc[mi][ni] = __builtin_amdgcn_mfma_f32_16x16x32_bf16(afh[mi], bh, acc[mi][ni], 0, 0, 0);
            }
        }
    }

    #pragma unroll
    for (int mi = 0; mi < 2; ++mi)
        #pragma unroll
        for (int r = 0; r < 4; ++r) {
            int node = node0 + mi * 16 + quad * 4 + r;
            if (node >= N) continue;
            #pragma unroll
            for (int ni = 0; ni < NI; ++ni) {
                int c = wave * (16 * NI) + ni * 16 + ml;
                float v = acc[mi][ni][r];
                if (c < DO) gs_out[(size_t)node * 128 + c] = v;
                else {
                    int cs = c - DO;
                    if (C == 256)
                        gnS_out[((size_t)(cs >> 4) * N + node) * 16 + (cs & 15)] = bf16_rne(v);
                    else
                        gnS_out[((size_t)(cs >> 3) * N + node) * 8 + (cs & 7)] = bf16_rne(v);
                }
            }
        }
}

// ---- final: sharded aggregate of gn4S + gs4 (strided in gs) -> out ----
__global__ __launch_bounds__(256, 4)
void agg_out_s(const float* __restrict__ gs,
               const unsigned short* __restrict__ gn4S,
               const int* __restrict__ neigh, const int* __restrict__ nodes,
               float* __restrict__ out, int N)
{
    const int s = blockIdx.x & 7;
    const int n = (blockIdx.x >> 3) * 256 + threadIdx.x;
    if (n >= N) return;
    const int nd = nodes[n];
    const int4* nb4 = (const int4*)(neigh + (size_t)nd * FANOUT);
    int4 q0 = nb4[0], q1 = nb4[1], q2 = nb4[2], q3 = nb4[3];
    int ids[FANOUT] = {q0.x, q0.y, q0.z, q0.w, q1.x, q1.y, q1.z, q1.w,
                       q2.x, q2.y, q2.z, q2.w, q3.x, q3.y, q3.z, q3.w};
    const unsigned short* base = gn4S + (size_t)s * N * 8;
    float acc[8];
    #pragma unroll
    for (int c = 0; c < 8; ++c) acc[c] = 0.f;
    #pragma unroll
    for (int j = 0; j < FANOUT; ++j) {
        uint4 q = *(const uint4*)(base + (size_t)ids[j] * 8);
        acc[0] += __uint_as_float(q.x << 16);
        acc[1] += __uint_as_float(q.x & 0xffff0000u);
        acc[2] += __uint_as_float(q.y << 16);
        acc[3] += __uint_as_float(q.y & 0xffff0000u);
        acc[4] += __uint_as_float(q.z << 16);
        acc[5] += __uint_as_float(q.z & 0xffff0000u);
        acc[6] += __uint_as_float(q.w << 16);
        acc[7] += __uint_as_float(q.w & 0xffff0000u);
    }
    const float inv = 1.0f / (float)FANOUT;
    const float* gp = gs + (size_t)nd * 128 + s * 8;
    float4 g0 = *(const float4*)(gp + 0);
    float4 g1 = *(const float4*)(gp + 4);
    float4 o0, o1;
    o0.x = fmaxf(fmaf(acc[0], inv, g0.x), 0.f);
    o0.y = fmaxf(fmaf(acc[1], inv, g0.y), 0.f);
    o0.z = fmaxf(fmaf(acc[2], inv, g0.z), 0.f);
    o0.w = fmaxf(fmaf(acc[3], inv, g0.w), 0.f);
    o1.x = fmaxf(fmaf(acc[4], inv, g1.x), 0.f);
    o1.y = fmaxf(fmaf(acc[5], inv, g1.y), 0.f);
    o1.z = fmaxf(fmaf(acc[6], inv, g1.z), 0.f);
    o1.w = fmaxf(fmaf(acc[7], inv, g1.w), 0.f);
    float* op = out + (size_t)n * 64 + s * 8;
    *(float4*)(op + 0) = o0;
    *(float4*)(op + 4) = o1;
}

extern "C" void kernel_launch(void* const* d_in, const int* in_sizes, int n_in,
                              void* d_out, int out_size, void* d_ws, size_t ws_size,
                              hipStream_t stream)
{
    const float* features = (const float*)d_in[0];
    const float* W1       = (const float*)d_in[1];
    const float* W2       = (const float*)d_in[2];
    const float* W3       = (const float*)d_in[3];
    const float* W4       = (const float*)d_in[4];
    const int*   nodes    = (const int*)d_in[5];
    const int*   neigh    = (const int*)d_in[6];
    float*       out      = (float*)d_out;

    unsigned short* B1h = (unsigned short*)d_ws;       // 65536
    unsigned short* B1l = B1h + 65536;
    unsigned short* B2h = B1l + 65536;                 // 32768
    unsigned short* B2l = B2h + 32768;
    unsigned short* B3h = B2l + 32768;
    unsigned short* B3l = B3h + 32768;
    unsigned short* B4h = B3l + 32768;                 // 16384
    unsigned short* B4l = B4h + 16384;
    float* gs = (float*)(B4l + 16384);                 // N*128 f32: gs / h (in-place)
    unsigned short* gnSA = (unsigned short*)(gs + (size_t)N_NODES * 128); // N*128 bf16 sharded
    unsigned short* gnSB = gnSA + (size_t)N_NODES * 128;                  // N*128 bf16 sharded
    unsigned short* gn4S = gnSB;                       // aliases gnSB (free at L4)

    prep_Bsw<<<(65536 + 255) / 256, 256, 0, stream>>>(W1, B1h, B1l, 256, 128);
    prep_Bsw<<<(32768 + 255) / 256, 256, 0, stream>>>(W2, B2h, B2l, 128, 128);
    prep_Bsw<<<(32768 + 255) / 256, 256, 0, stream>>>(W3, B3h, B3l, 128, 128);
    prep_Bsw<<<(16384 + 255) / 256, 256, 0, stream>>>(W4, B4h, B4l, 128, 64);

    const int grid32 = (N_NODES + 31) / 32;            // 3125
    const int gridA  = ((N_NODES + 255) / 256) * 8;    // 391*8 = 3128

    gemm1<<<grid32, 256, 0, stream>>>(features, B1h, B1l, gs, gnSA, N_NODES);
    agg_act<<<gridA, 256, 0, stream>>>(gnSA, neigh, gs, N_NODES);
    gemm_mid<256><<<grid32, 256, 0, stream>>>(gs, B2h, B2l, gs, gnSB, N_NODES);
    agg_act<<<gridA, 256, 0, stream>>>(gnSB, neigh, gs, N_NODES);
    gemm_mid<256><<<grid32, 256, 0, stream>>>(gs, B3h, B3l, gs, gnSA, N_NODES);
    agg_act<<<gridA, 256, 0, stream>>>(gnSA, neigh, gs, N_NODES);
    gemm_mid<128><<<grid32, 256, 0, stream>>>(gs, B4h, B4l, gs, gn4S, N_NODES);
    agg_out_s<<<gridA, 256, 0, stream>>>(gs, gn4S, neigh, nodes, out, N_NODES);
}

// Round 9
// 469.846 us; speedup vs baseline: 1.5673x; 1.5673x over previous
//
#include <hip/hip_runtime.h>
#include <hip/hip_bf16.h>

// GraphSAGE R14: revert to R10 dataflow (best: 457us; R13 split regressed
// 736us via 32B-slice line waste + gs round-trip). Two safe levers:
//  (1) gemm1: preload ALL 8 A-chunks (32 VGPR in flight, const offsets from
//      one base -> compiler clusters them, unlike R12's gather) -> 8-deep
//      feature stream. launch_bounds(256,4): 32 AGPR+32 pf+~40 work <= 128.
//  (2) nontemporal LOADS on streamed-once data (hf, gs rows, neigh) to stop
//      them evicting the L2 gather working set (currently ~50% hit).
//      Stores left normal (gn is gathered next layer; avoid LLC-bypass risk).
// fused_layer = R10 exact config (256,6)/VGPR40/16KB LDS/quad-coalesced.

constexpr int N_NODES = 100000;
constexpr int FANOUT  = 16;

typedef __attribute__((ext_vector_type(8))) short short8;
typedef __attribute__((ext_vector_type(4))) float f32x4;
typedef __attribute__((ext_vector_type(4))) int   i32x4;
typedef __attribute__((ext_vector_type(4))) unsigned int u32x4;

__device__ inline unsigned short bf16_rne(float f) {
    unsigned u = __float_as_uint(f);
    return (unsigned short)((u + 0x7fffu + ((u >> 16) & 1u)) >> 16);
}
__device__ inline float bf16_tof(unsigned short s) {
    return __uint_as_float(((unsigned)s) << 16);
}

// ---- weights -> hi/lo bf16, FRAGMENT-SWIZZLED layout ----
// off(c,k) = ((tk*(C/16)+tc)*64 + qk*16 + mlc)*8 + e
__global__ __launch_bounds__(256)
void prep_Bsw(const float* __restrict__ W, unsigned short* __restrict__ Bhi,
              unsigned short* __restrict__ Blo, int D_IN, int D_OUT)
{
    int i = blockIdx.x * 256 + threadIdx.x;
    int total = 2 * D_OUT * D_IN;
    if (i >= total) return;
    int K = D_IN, C = 2 * D_OUT;
    int c = i / K, k = i % K;
    float v = (c < D_OUT) ? W[(size_t)c * (2 * K) + k]
                          : W[(size_t)(c - D_OUT) * (2 * K) + K + k];
    int tc = c >> 4, mlc = c & 15;
    int tk = k >> 5, qk = (k >> 3) & 3, e = k & 7;
    size_t off = ((size_t)(tk * (C / 16) + tc) * 64 + qk * 16 + mlc) * 8 + e;
    unsigned short hi = bf16_rne(v);
    Bhi[off] = hi;
    Blo[off] = bf16_rne(v - bf16_tof(hi));
}

// ---- gemm1: dense, K=256, C=256. block = 32 nodes, 8-deep A preload. ----
__global__ __launch_bounds__(256, 4)
void gemm1(const float* __restrict__ hf,
           const unsigned short* __restrict__ Bhi,
           const unsigned short* __restrict__ Blo,
           float* __restrict__ gs, unsigned short* __restrict__ gn, int N)
{
    constexpr int K = 256, DO = 128, LDA = 40;
    __shared__ unsigned short Ah[32 * LDA], Al[32 * LDA];

    const int tid  = threadIdx.x;
    const int wave = tid >> 6;
    const int lane = tid & 63;
    const int ml   = lane & 15;
    const int quad = lane >> 4;
    const int node0 = blockIdx.x * 32;

    const int srow = tid >> 3;
    const int sc4  = tid & 7;
    int nd = node0 + srow; if (nd >= N) nd = N - 1;
    const float* pA = &hf[(size_t)nd * K + sc4 * 4];

    // preload the whole row slice: 8 chunks, all in flight (32 VGPR)
    f32x4 pfa[8];
    #pragma unroll
    for (int t = 0; t < 8; ++t)
        pfa[t] = __builtin_nontemporal_load((const f32x4*)(pA + 32 * t));

    f32x4 acc[2][4];
    #pragma unroll
    for (int mi = 0; mi < 2; ++mi)
        #pragma unroll
        for (int ni = 0; ni < 4; ++ni)
            acc[mi][ni] = (f32x4){0.f, 0.f, 0.f, 0.f};

    #pragma unroll
    for (int kt = 0; kt < 8; ++kt) {
        const int k0 = kt * 32;
        {
            float vv[4] = {pfa[kt][0], pfa[kt][1], pfa[kt][2], pfa[kt][3]};
            unsigned short hi[4], lo[4];
            #pragma unroll
            for (int e = 0; e < 4; ++e) {
                hi[e] = bf16_rne(vv[e]);
                lo[e] = bf16_rne(vv[e] - bf16_tof(hi[e]));
            }
            *(uint2*)&Ah[srow * LDA + sc4 * 4] = *(const uint2*)hi;
            *(uint2*)&Al[srow * LDA + sc4 * 4] = *(const uint2*)lo;
        }
        __syncthreads();

        short8 afh[2], afl[2];
        #pragma unroll
        for (int mi = 0; mi < 2; ++mi) {
            int r = mi * 16 + ml;
            afh[mi] = *(const short8*)&Ah[r * LDA + quad * 8];
            afl[mi] = *(const short8*)&Al[r * LDA + quad * 8];
        }
        const size_t bbase = (size_t)(kt * 16 + wave * 4) * 512 + (size_t)lane * 8;
        #pragma unroll
        for (int ni = 0; ni < 4; ++ni) {
            short8 bh = *(const short8*)&Bhi[bbase + ni * 512];
            short8 bl = *(const short8*)&Blo[bbase + ni * 512];
            #pragma unroll
            for (int mi = 0; mi < 2; ++mi) {
                acc[mi][ni] = __builtin_amdgcn_mfma_f32_16x16x32_bf16(afl[mi], bh, acc[mi][ni], 0, 0, 0);
                acc[mi][ni] = __builtin_amdgcn_mfma_f32_16x16x32_bf16(afh[mi], bl, acc[mi][ni], 0, 0, 0);
                acc[mi][ni] = __builtin_amdgcn_mfma_f32_16x16x32_bf16(afh[mi], bh, acc[mi][ni], 0, 0, 0);
            }
        }
        __syncthreads();
    }

    #pragma unroll
    for (int mi = 0; mi < 2; ++mi)
        #pragma unroll
        for (int r = 0; r < 4; ++r) {
            int node = node0 + mi * 16 + quad * 4 + r;
            if (node >= N) continue;
            #pragma unroll
            for (int ni = 0; ni < 4; ++ni) {
                int c = wave * 64 + ni * 16 + ml;
                float v = acc[mi][ni][r];
                if (c < DO) gs[(size_t)node * DO + c] = v;
                else        gn[(size_t)node * DO + (c - DO)] = bf16_rne(v);
            }
        }
}

// ---- fused layer: R10 config. 32 nodes/block, quad-coalesced gather,
// XOR-swizzled A LDS, barrier-free k-loop, fragment-swizzled B (L2). ----
template<int C>
__global__ __launch_bounds__(256, 6)
void fused_layer(const float* __restrict__ gs_in,
                 const unsigned short* __restrict__ gn_in,
                 const int* __restrict__ neigh,
                 const unsigned short* __restrict__ Bhi,
                 const unsigned short* __restrict__ Blo,
                 float* __restrict__ gs_out,
                 unsigned short* __restrict__ gn_out, int N)
{
    constexpr int K = 128, DO = C / 2, NI = C / 64;
    __shared__ unsigned short Afh[32 * 128], Afl[32 * 128];   // 16384 B total

    const int tid  = threadIdx.x;
    const int wave = tid >> 6;
    const int lane = tid & 63;
    const int ml   = lane & 15;
    const int quad = lane >> 4;
    const int node0 = blockIdx.x * 32;

    // ---- A-phase: h = relu(gs + mean*gn[nb]); 8 threads/row, thread s
    // owns chunks c0=64(s>>2)+8(s&3), c1=c0+32 (quad = one full 64B line).
    {
        const int row = tid >> 3;          // node within block (0..31)
        const int s   = tid & 7;
        const int c0  = 64 * (s >> 2) + 8 * (s & 3);
        const int c1  = c0 + 32;
        int nd = node0 + row; if (nd >= N) nd = N - 1;
        const i32x4* nb4 = (const i32x4*)(neigh + (size_t)nd * FANOUT);
        i32x4 q0 = __builtin_nontemporal_load(nb4 + 0);
        i32x4 q1 = __builtin_nontemporal_load(nb4 + 1);
        i32x4 q2 = __builtin_nontemporal_load(nb4 + 2);
        i32x4 q3 = __builtin_nontemporal_load(nb4 + 3);
        int ids[FANOUT] = {q0[0], q0[1], q0[2], q0[3], q1[0], q1[1], q1[2], q1[3],
                           q2[0], q2[1], q2[2], q2[3], q3[0], q3[1], q3[2], q3[3]};
        float acc[16];
        #pragma unroll
        for (int c = 0; c < 16; ++c) acc[c] = 0.f;
        #pragma unroll
        for (int j = 0; j < FANOUT; ++j) {
            const uint4* src = (const uint4*)&gn_in[(size_t)ids[j] * 128];
            uint4 qa = src[c0 >> 3];
            uint4 qb = src[c1 >> 3];
            acc[0]  += __uint_as_float(qa.x << 16);
            acc[1]  += __uint_as_float(qa.x & 0xffff0000u);
            acc[2]  += __uint_as_float(qa.y << 16);
            acc[3]  += __uint_as_float(qa.y & 0xffff0000u);
            acc[4]  += __uint_as_float(qa.z << 16);
            acc[5]  += __uint_as_float(qa.z & 0xffff0000u);
            acc[6]  += __uint_as_float(qa.w << 16);
            acc[7]  += __uint_as_float(qa.w & 0xffff0000u);
            acc[8]  += __uint_as_float(qb.x << 16);
            acc[9]  += __uint_as_float(qb.x & 0xffff0000u);
            acc[10] += __uint_as_float(qb.y << 16);
            acc[11] += __uint_as_float(qb.y & 0xffff0000u);
            acc[12] += __uint_as_float(qb.z << 16);
            acc[13] += __uint_as_float(qb.z & 0xffff0000u);
            acc[14] += __uint_as_float(qb.w << 16);
            acc[15] += __uint_as_float(qb.w & 0xffff0000u);
        }
        const float inv = 1.0f / (float)FANOUT;
        const float* gsp = &gs_in[(size_t)nd * 128];
        #pragma unroll
        for (int cc = 0; cc < 2; ++cc) {
            const int ch = cc ? c1 : c0;
            f32x4 g0 = __builtin_nontemporal_load((const f32x4*)(gsp + ch));
            f32x4 g1 = __builtin_nontemporal_load((const f32x4*)(gsp + ch + 4));
            float sv[8] = {g0[0], g0[1], g0[2], g0[3], g1[0], g1[1], g1[2], g1[3]};
            alignas(16) unsigned short th[8], tl[8];
            #pragma unroll
            for (int e = 0; e < 8; ++e) {
                float h = fmaxf(fmaf(acc[cc * 8 + e], inv, sv[e]), 0.f);
                unsigned short hi = bf16_rne(h);
                th[e] = hi;
                tl[e] = bf16_rne(h - bf16_tof(hi));
            }
            int soff = (row * 128 + ch) ^ ((row & 7) << 3);
            *(uint4*)&Afh[soff] = *(const uint4*)th;
            *(uint4*)&Afl[soff] = *(const uint4*)tl;
        }
    }
    __syncthreads();

    f32x4 acc[2][NI];
    #pragma unroll
    for (int mi = 0; mi < 2; ++mi)
        #pragma unroll
        for (int ni = 0; ni < NI; ++ni)
            acc[mi][ni] = (f32x4){0.f, 0.f, 0.f, 0.f};

    // barrier-free k-loop: A from swizzled LDS, B fragment-swizzled global
    for (int k0 = 0; k0 < K; k0 += 32) {
        short8 afh[2], afl[2];
        #pragma unroll
        for (int mi = 0; mi < 2; ++mi) {
            int r = mi * 16 + ml;
            int soff = (r * 128 + k0 + quad * 8) ^ ((r & 7) << 3);
            afh[mi] = *(const short8*)&Afh[soff];
            afl[mi] = *(const short8*)&Afl[soff];
        }
        const size_t bbase = (size_t)((k0 >> 5) * (C / 16) + wave * NI) * 512 + (size_t)lane * 8;
        #pragma unroll
        for (int ni = 0; ni < NI; ++ni) {
            short8 bh = *(const short8*)&Bhi[bbase + ni * 512];
            short8 bl = *(const short8*)&Blo[bbase + ni * 512];
            #pragma unroll
            for (int mi = 0; mi < 2; ++mi) {
                acc[mi][ni] = __builtin_amdgcn_mfma_f32_16x16x32_bf16(afl[mi], bh, acc[mi][ni], 0, 0, 0);
                acc[mi][ni] = __builtin_amdgcn_mfma_f32_16x16x32_bf16(afh[mi], bl, acc[mi][ni], 0, 0, 0);
                acc[mi][ni] = __builtin_amdgcn_mfma_f32_16x16x32_bf16(afh[mi], bh, acc[mi][ni], 0, 0, 0);
            }
        }
    }

    #pragma unroll
    for (int mi = 0; mi < 2; ++mi)
        #pragma unroll
        for (int r = 0; r < 4; ++r) {
            int node = node0 + mi * 16 + quad * 4 + r;
            if (node >= N) continue;
            #pragma unroll
            for (int ni = 0; ni < NI; ++ni) {
                int c = wave * (16 * NI) + ni * 16 + ml;
                float v = acc[mi][ni][r];
                if (c < DO) gs_out[(size_t)node * DO + c] = v;
                else        gn_out[(size_t)node * DO + (c - DO)] = bf16_rne(v);
            }
        }
}

// ---- final: out[i] = relu(gs4[nodes[i]] + mean_j gn4[nb[j]]), D_OUT=64 ----
__global__ __launch_bounds__(256)
void agg_out(const float* __restrict__ gs4, const unsigned short* __restrict__ gn4,
             const int* __restrict__ neigh, const int* __restrict__ nodes,
             float* __restrict__ out, int N)
{
    const int i    = blockIdx.x * 32 + (threadIdx.x >> 3);
    const int lane = threadIdx.x & 7;
    if (i >= N) return;
    const int nd = nodes[i];
    const i32x4* nb4 = (const i32x4*)(neigh + (size_t)nd * FANOUT);
    i32x4 q0 = __builtin_nontemporal_load(nb4 + 0);
    i32x4 q1 = __builtin_nontemporal_load(nb4 + 1);
    i32x4 q2 = __builtin_nontemporal_load(nb4 + 2);
    i32x4 q3 = __builtin_nontemporal_load(nb4 + 3);
    int ids[FANOUT] = {q0[0], q0[1], q0[2], q0[3], q1[0], q1[1], q1[2], q1[3],
                       q2[0], q2[1], q2[2], q2[3], q3[0], q3[1], q3[2], q3[3]};
    float acc[8];
    #pragma unroll
    for (int c = 0; c < 8; ++c) acc[c] = 0.f;
    #pragma unroll
    for (int j = 0; j < FANOUT; ++j) {
        uint4 q = *(const uint4*)&gn4[(size_t)ids[j] * 64 + lane * 8];
        acc[0] += __uint_as_float(q.x << 16);
        acc[1] += __uint_as_float(q.x & 0xffff0000u);
        acc[2] += __uint_as_float(q.y << 16);
        acc[3] += __uint_as_float(q.y & 0xffff0000u);
        acc[4] += __uint_as_float(q.z << 16);
        acc[5] += __uint_as_float(q.z & 0xffff0000u);
        acc[6] += __uint_as_float(q.w << 16);
        acc[7] += __uint_as_float(q.w & 0xffff0000u);
    }
    const float inv = 1.0f / (float)FANOUT;
    const float* s = gs4 + (size_t)nd * 64 + lane * 8;
    f32x4 s0 = __builtin_nontemporal_load((const f32x4*)(s + 0));
    f32x4 s1 = __builtin_nontemporal_load((const f32x4*)(s + 4));
    float4 o0, o1;
    o0.x = fmaxf(fmaf(acc[0], inv, s0[0]), 0.f);
    o0.y = fmaxf(fmaf(acc[1], inv, s0[1]), 0.f);
    o0.z = fmaxf(fmaf(acc[2], inv, s0[2]), 0.f);
    o0.w = fmaxf(fmaf(acc[3], inv, s0[3]), 0.f);
    o1.x = fmaxf(fmaf(acc[4], inv, s1[0]), 0.f);
    o1.y = fmaxf(fmaf(acc[5], inv, s1[1]), 0.f);
    o1.z = fmaxf(fmaf(acc[6], inv, s1[2]), 0.f);
    o1.w = fmaxf(fmaf(acc[7], inv, s1[3]), 0.f);
    float* op = out + (size_t)i * 64 + lane * 8;
    *(float4*)&op[0] = o0;
    *(float4*)&op[4] = o1;
}

extern "C" void kernel_launch(void* const* d_in, const int* in_sizes, int n_in,
                              void* d_out, int out_size, void* d_ws, size_t ws_size,
                              hipStream_t stream)
{
    const float* features = (const float*)d_in[0];
    const float* W1       = (const float*)d_in[1];
    const float* W2       = (const float*)d_in[2];
    const float* W3       = (const float*)d_in[3];
    const float* W4       = (const float*)d_in[4];
    const int*   nodes    = (const int*)d_in[5];
    const int*   neigh    = (const int*)d_in[6];
    float*       out      = (float*)d_out;

    unsigned short* B1h = (unsigned short*)d_ws;       // 65536
    unsigned short* B1l = B1h + 65536;
    unsigned short* B2h = B1l + 65536;                 // 32768
    unsigned short* B2l = B2h + 32768;
    unsigned short* B3h = B2l + 32768;
    unsigned short* B3l = B3h + 32768;
    unsigned short* B4h = B3l + 32768;                 // 16384
    unsigned short* B4l = B4h + 16384;
    float* gs = (float*)(B4l + 16384);                 // N*128 fp32, in-place L1-L3
    unsigned short* gnA = (unsigned short*)(gs + (size_t)N_NODES * 128); // N*128 bf16
    unsigned short* gnB = gnA + (size_t)N_NODES * 128; // N*128 bf16
    float* gs4 = (float*)gnB;                          // aliases gnB (free at L4)
    unsigned short* gn4 = gnB + (size_t)N_NODES * 128; // N*64 bf16

    prep_Bsw<<<(65536 + 255) / 256, 256, 0, stream>>>(W1, B1h, B1l, 256, 128);
    prep_Bsw<<<(32768 + 255) / 256, 256, 0, stream>>>(W2, B2h, B2l, 128, 128);
    prep_Bsw<<<(32768 + 255) / 256, 256, 0, stream>>>(W3, B3h, B3l, 128, 128);
    prep_Bsw<<<(16384 + 255) / 256, 256, 0, stream>>>(W4, B4h, B4l, 128, 64);

    const int grid32 = (N_NODES + 31) / 32;   // 3125

    gemm1<<<grid32, 256, 0, stream>>>(features, B1h, B1l, gs, gnA, N_NODES);
    fused_layer<256><<<grid32, 256, 0, stream>>>(gs, gnA, neigh, B2h, B2l, gs, gnB, N_NODES);
    fused_layer<256><<<grid32, 256, 0, stream>>>(gs, gnB, neigh, B3h, B3l, gs, gnA, N_NODES);
    fused_layer<128><<<grid32, 256, 0, stream>>>(gs, gnA, neigh, B4h, B4l, gs4, gn4, N_NODES);
    agg_out<<<(N_NODES + 31) / 32, 256, 0, stream>>>(gs4, gn4, neigh, nodes, out, N_NODES);
}

// Round 10
// 449.637 us; speedup vs baseline: 1.6377x; 1.0449x over previous
//
#include <hip/hip_runtime.h>
#include <hip/hip_bf16.h>

// GraphSAGE R15: exact R10 revert (best measured, 456.6us) + merged prep.
//  R14 attribution: nt-load hints cost ~3us/fused with FETCH unchanged ->
//  reverted. Fused gather plateaus at 3.5-3.65 TB/s across occupancy/ILP/
//  shard/hint levers (R9-R14) = random 64B-line L2-miss/LLC fabric knee;
//  FETCH ~210MB is the structural floor (25.6MB random table vs 4MB L2,
//  full lines consumed). This config is the roofline operating point.
//  Change vs R10: 4x prep_Bsw -> 1 prep_all launch (fewer launch gaps).

constexpr int N_NODES = 100000;
constexpr int FANOUT  = 16;

typedef __attribute__((ext_vector_type(8))) short short8;
typedef __attribute__((ext_vector_type(4))) float f32x4;

__device__ inline unsigned short bf16_rne(float f) {
    unsigned u = __float_as_uint(f);
    return (unsigned short)((u + 0x7fffu + ((u >> 16) & 1u)) >> 16);
}
__device__ inline float bf16_tof(unsigned short s) {
    return __uint_as_float(((unsigned)s) << 16);
}

// ---- all weights -> hi/lo bf16, FRAGMENT-SWIZZLED layout, one launch ----
// off(c,k) = ((tk*(C/16)+tc)*64 + qk*16 + mlc)*8 + e
//   tc=c>>4, mlc=c&15, tk=k>>5, qk=(k>>3)&3, e=k&7
__device__ inline void prep_one(const float* __restrict__ W,
                                unsigned short* __restrict__ Bhi,
                                unsigned short* __restrict__ Blo,
                                int idx, int D_IN, int D_OUT)
{
    int K = D_IN, C = 2 * D_OUT;
    int c = idx / K, k = idx % K;
    float v = (c < D_OUT) ? W[(size_t)c * (2 * K) + k]
                          : W[(size_t)(c - D_OUT) * (2 * K) + K + k];
    int tc = c >> 4, mlc = c & 15;
    int tk = k >> 5, qk = (k >> 3) & 3, e = k & 7;
    size_t off = ((size_t)(tk * (C / 16) + tc) * 64 + qk * 16 + mlc) * 8 + e;
    unsigned short hi = bf16_rne(v);
    Bhi[off] = hi;
    Blo[off] = bf16_rne(v - bf16_tof(hi));
}

__global__ __launch_bounds__(256)
void prep_all(const float* __restrict__ W1, const float* __restrict__ W2,
              const float* __restrict__ W3, const float* __restrict__ W4,
              unsigned short* __restrict__ B1h, unsigned short* __restrict__ B1l,
              unsigned short* __restrict__ B2h, unsigned short* __restrict__ B2l,
              unsigned short* __restrict__ B3h, unsigned short* __restrict__ B3l,
              unsigned short* __restrict__ B4h, unsigned short* __restrict__ B4l)
{
    int i = blockIdx.x * 256 + threadIdx.x;
    if (i < 65536)       prep_one(W1, B1h, B1l, i,           256, 128);
    else if (i < 98304)  prep_one(W2, B2h, B2l, i - 65536,   128, 128);
    else if (i < 131072) prep_one(W3, B3h, B3l, i - 98304,   128, 128);
    else if (i < 147456) prep_one(W4, B4h, B4l, i - 131072,  128, 64);
}

// ---- gemm1: dense, K=256, C=256. block = 64 nodes, wave tile 64x64. ----
// Software-pipelined A staging (fp32 -> split bf16); fragment-swizzled B
// read straight from global (L2-hot, no B LDS).
__global__ __launch_bounds__(256, 3)
void gemm1(const float* __restrict__ hf,
           const unsigned short* __restrict__ Bhi,
           const unsigned short* __restrict__ Blo,
           float* __restrict__ gs, unsigned short* __restrict__ gn, int N)
{
    constexpr int K = 256, DO = 128, LDA = 40;
    __shared__ unsigned short Ah[64 * LDA], Al[64 * LDA];

    const int tid  = threadIdx.x;
    const int wave = tid >> 6;
    const int lane = tid & 63;
    const int ml   = lane & 15;
    const int quad = lane >> 4;
    const int node0 = blockIdx.x * 64;

    const int srow = tid >> 3;
    const int sc4  = tid & 7;
    int nd0 = node0 + srow;      if (nd0 >= N) nd0 = N - 1;
    int nd1 = node0 + srow + 32; if (nd1 >= N) nd1 = N - 1;
    const float* pA0 = &hf[(size_t)nd0 * K + sc4 * 4];
    const float* pA1 = &hf[(size_t)nd1 * K + sc4 * 4];

    f32x4 acc[4][4];
    #pragma unroll
    for (int mi = 0; mi < 4; ++mi)
        #pragma unroll
        for (int ni = 0; ni < 4; ++ni)
            acc[mi][ni] = (f32x4){0.f, 0.f, 0.f, 0.f};

    float4 pf0 = *(const float4*)&pA0[0];
    float4 pf1 = *(const float4*)&pA1[0];

    for (int k0 = 0; k0 < K; k0 += 32) {
        {
            float v0[4] = {pf0.x, pf0.y, pf0.z, pf0.w};
            float v1[4] = {pf1.x, pf1.y, pf1.z, pf1.w};
            unsigned short h0[4], l0[4], h1[4], l1[4];
            #pragma unroll
            for (int e = 0; e < 4; ++e) {
                h0[e] = bf16_rne(v0[e]); l0[e] = bf16_rne(v0[e] - bf16_tof(h0[e]));
                h1[e] = bf16_rne(v1[e]); l1[e] = bf16_rne(v1[e] - bf16_tof(h1[e]));
            }
            *(uint2*)&Ah[srow * LDA + sc4 * 4]        = *(const uint2*)h0;
            *(uint2*)&Al[srow * LDA + sc4 * 4]        = *(const uint2*)l0;
            *(uint2*)&Ah[(srow + 32) * LDA + sc4 * 4] = *(const uint2*)h1;
            *(uint2*)&Al[(srow + 32) * LDA + sc4 * 4] = *(const uint2*)l1;
        }
        if (k0 + 32 < K) {
            pf0 = *(const float4*)&pA0[k0 + 32];
            pf1 = *(const float4*)&pA1[k0 + 32];
        }
        __syncthreads();

        short8 afh[4], afl[4];
        #pragma unroll
        for (int mi = 0; mi < 4; ++mi) {
            int r = mi * 16 + ml;
            afh[mi] = *(const short8*)&Ah[r * LDA + quad * 8];
            afl[mi] = *(const short8*)&Al[r * LDA + quad * 8];
        }
        const size_t bbase = (size_t)((k0 >> 5) * 16 + wave * 4) * 512 + (size_t)lane * 8;
        #pragma unroll
        for (int ni = 0; ni < 4; ++ni) {
            short8 bh = *(const short8*)&Bhi[bbase + ni * 512];
            short8 bl = *(const short8*)&Blo[bbase + ni * 512];
            #pragma unroll
            for (int mi = 0; mi < 4; ++mi) {
                acc[mi][ni] = __builtin_amdgcn_mfma_f32_16x16x32_bf16(afl[mi], bh, acc[mi][ni], 0, 0, 0);
                acc[mi][ni] = __builtin_amdgcn_mfma_f32_16x16x32_bf16(afh[mi], bl, acc[mi][ni], 0, 0, 0);
                acc[mi][ni] = __builtin_amdgcn_mfma_f32_16x16x32_bf16(afh[mi], bh, acc[mi][ni], 0, 0, 0);
            }
        }
        __syncthreads();
    }

    #pragma unroll
    for (int mi = 0; mi < 4; ++mi)
        #pragma unroll
        for (int r = 0; r < 4; ++r) {
            int node = node0 + mi * 16 + quad * 4 + r;
            if (node >= N) continue;
            #pragma unroll
            for (int ni = 0; ni < 4; ++ni) {
                int c = wave * 64 + ni * 16 + ml;
                float v = acc[mi][ni][r];
                if (c < DO) gs[(size_t)node * DO + c] = v;
                else        gn[(size_t)node * DO + (c - DO)] = bf16_rne(v);
            }
        }
}

// ---- fused layer: 32 nodes/block (R10 config: VGPR 40, 16KB LDS, 6/CU) ----
// D_IN=128 fixed. C=256 (DO=128, NI=4) or C=128 (DO=64, NI=2).
template<int C>
__global__ __launch_bounds__(256, 6)
void fused_layer(const float* __restrict__ gs_in,
                 const unsigned short* __restrict__ gn_in,
                 const int* __restrict__ neigh,
                 const unsigned short* __restrict__ Bhi,
                 const unsigned short* __restrict__ Blo,
                 float* __restrict__ gs_out,
                 unsigned short* __restrict__ gn_out, int N)
{
    constexpr int K = 128, DO = C / 2, NI = C / 64;
    __shared__ unsigned short Afh[32 * 128], Afl[32 * 128];   // 16384 B total

    const int tid  = threadIdx.x;
    const int wave = tid >> 6;
    const int lane = tid & 63;
    const int ml   = lane & 15;
    const int quad = lane >> 4;
    const int node0 = blockIdx.x * 32;

    // ---- A-phase: h = relu(gs + mean*gn[nb]); 8 threads/row, thread s
    // owns chunks c0=64(s>>2)+8(s&3), c1=c0+32 -> each quad load
    // instruction covers one full 64B line of the neighbor row.
    {
        const int row = tid >> 3;          // node within block (0..31)
        const int s   = tid & 7;
        const int c0  = 64 * (s >> 2) + 8 * (s & 3);
        const int c1  = c0 + 32;
        int nd = node0 + row; if (nd >= N) nd = N - 1;
        const int4* nb4 = (const int4*)(neigh + (size_t)nd * FANOUT);
        int4 q0 = nb4[0], q1 = nb4[1], q2 = nb4[2], q3 = nb4[3];
        int ids[FANOUT] = {q0.x, q0.y, q0.z, q0.w, q1.x, q1.y, q1.z, q1.w,
                           q2.x, q2.y, q2.z, q2.w, q3.x, q3.y, q3.z, q3.w};
        float acc[16];
        #pragma unroll
        for (int c = 0; c < 16; ++c) acc[c] = 0.f;
        #pragma unroll
        for (int j = 0; j < FANOUT; ++j) {
            const uint4* src = (const uint4*)&gn_in[(size_t)ids[j] * 128];
            uint4 qa = src[c0 >> 3];
            uint4 qb = src[c1 >> 3];
            acc[0]  += __uint_as_float(qa.x << 16);
            acc[1]  += __uint_as_float(qa.x & 0xffff0000u);
            acc[2]  += __uint_as_float(qa.y << 16);
            acc[3]  += __uint_as_float(qa.y & 0xffff0000u);
            acc[4]  += __uint_as_float(qa.z << 16);
            acc[5]  += __uint_as_float(qa.z & 0xffff0000u);
            acc[6]  += __uint_as_float(qa.w << 16);
            acc[7]  += __uint_as_float(qa.w & 0xffff0000u);
            acc[8]  += __uint_as_float(qb.x << 16);
            acc[9]  += __uint_as_float(qb.x & 0xffff0000u);
            acc[10] += __uint_as_float(qb.y << 16);
            acc[11] += __uint_as_float(qb.y & 0xffff0000u);
            acc[12] += __uint_as_float(qb.z << 16);
            acc[13] += __uint_as_float(qb.z & 0xffff0000u);
            acc[14] += __uint_as_float(qb.w << 16);
            acc[15] += __uint_as_float(qb.w & 0xffff0000u);
        }
        const float inv = 1.0f / (float)FANOUT;
        const float* gsp = &gs_in[(size_t)nd * 128];
        #pragma unroll
        for (int cc = 0; cc < 2; ++cc) {
            const int ch = cc ? c1 : c0;
            float4 g0 = *(const float4*)&gsp[ch];
            float4 g1 = *(const float4*)&gsp[ch + 4];
            float sv[8] = {g0.x, g0.y, g0.z, g0.w, g1.x, g1.y, g1.z, g1.w};
            alignas(16) unsigned short th[8], tl[8];
            #pragma unroll
            for (int e = 0; e < 8; ++e) {
                float h = fmaxf(fmaf(acc[cc * 8 + e], inv, sv[e]), 0.f);
                unsigned short hi = bf16_rne(h);
                th[e] = hi;
                tl[e] = bf16_rne(h - bf16_tof(hi));
            }
            int soff = (row * 128 + ch) ^ ((row & 7) << 3);
            *(uint4*)&Afh[soff] = *(const uint4*)th;
            *(uint4*)&Afl[soff] = *(const uint4*)tl;
        }
    }
    __syncthreads();

    f32x4 acc[2][NI];
    #pragma unroll
    for (int mi = 0; mi < 2; ++mi)
        #pragma unroll
        for (int ni = 0; ni < NI; ++ni)
            acc[mi][ni] = (f32x4){0.f, 0.f, 0.f, 0.f};

    // barrier-free k-loop: A from swizzled LDS, B fragment-swizzled global
    for (int k0 = 0; k0 < K; k0 += 32) {
        short8 afh[2], afl[2];
        #pragma unroll
        for (int mi = 0; mi < 2; ++mi) {
            int r = mi * 16 + ml;
            int soff = (r * 128 + k0 + quad * 8) ^ ((r & 7) << 3);
            afh[mi] = *(const short8*)&Afh[soff];
            afl[mi] = *(const short8*)&Afl[soff];
        }
        const size_t bbase = (size_t)((k0 >> 5) * (C / 16) + wave * NI) * 512 + (size_t)lane * 8;
        #pragma unroll
        for (int ni = 0; ni < NI; ++ni) {
            short8 bh = *(const short8*)&Bhi[bbase + ni * 512];
            short8 bl = *(const short8*)&Blo[bbase + ni * 512];
            #pragma unroll
            for (int mi = 0; mi < 2; ++mi) {
                acc[mi][ni] = __builtin_amdgcn_mfma_f32_16x16x32_bf16(afl[mi], bh, acc[mi][ni], 0, 0, 0);
                acc[mi][ni] = __builtin_amdgcn_mfma_f32_16x16x32_bf16(afh[mi], bl, acc[mi][ni], 0, 0, 0);
                acc[mi][ni] = __builtin_amdgcn_mfma_f32_16x16x32_bf16(afh[mi], bh, acc[mi][ni], 0, 0, 0);
            }
        }
    }

    #pragma unroll
    for (int mi = 0; mi < 2; ++mi)
        #pragma unroll
        for (int r = 0; r < 4; ++r) {
            int node = node0 + mi * 16 + quad * 4 + r;
            if (node >= N) continue;
            #pragma unroll
            for (int ni = 0; ni < NI; ++ni) {
                int c = wave * (16 * NI) + ni * 16 + ml;
                float v = acc[mi][ni][r];
                if (c < DO) gs_out[(size_t)node * DO + c] = v;
                else        gn_out[(size_t)node * DO + (c - DO)] = bf16_rne(v);
            }
        }
}

// ---- final: out[i] = relu(gs4[nodes[i]] + mean_j gn4[nb[j]]), D_OUT=64 ----
__global__ __launch_bounds__(256)
void agg_out(const float* __restrict__ gs4, const unsigned short* __restrict__ gn4,
             const int* __restrict__ neigh, const int* __restrict__ nodes,
             float* __restrict__ out, int N)
{
    const int i    = blockIdx.x * 32 + (threadIdx.x >> 3);
    const int lane = threadIdx.x & 7;
    if (i >= N) return;
    const int nd = nodes[i];
    const int4* nb4 = (const int4*)(neigh + (size_t)nd * FANOUT);
    int4 q0 = nb4[0], q1 = nb4[1], q2 = nb4[2], q3 = nb4[3];
    int ids[FANOUT] = {q0.x, q0.y, q0.z, q0.w, q1.x, q1.y, q1.z, q1.w,
                       q2.x, q2.y, q2.z, q2.w, q3.x, q3.y, q3.z, q3.w};
    float acc[8];
    #pragma unroll
    for (int c = 0; c < 8; ++c) acc[c] = 0.f;
    #pragma unroll
    for (int j = 0; j < FANOUT; ++j) {
        uint4 q = *(const uint4*)&gn4[(size_t)ids[j] * 64 + lane * 8];
        acc[0] += __uint_as_float(q.x << 16);
        acc[1] += __uint_as_float(q.x & 0xffff0000u);
        acc[2] += __uint_as_float(q.y << 16);
        acc[3] += __uint_as_float(q.y & 0xffff0000u);
        acc[4] += __uint_as_float(q.z << 16);
        acc[5] += __uint_as_float(q.z & 0xffff0000u);
        acc[6] += __uint_as_float(q.w << 16);
        acc[7] += __uint_as_float(q.w & 0xffff0000u);
    }
    const float inv = 1.0f / (float)FANOUT;
    const float* s = gs4 + (size_t)nd * 64 + lane * 8;
    float4 s0 = *(const float4*)&s[0];
    float4 s1 = *(const float4*)&s[4];
    float4 o0, o1;
    o0.x = fmaxf(fmaf(acc[0], inv, s0.x), 0.f);
    o0.y = fmaxf(fmaf(acc[1], inv, s0.y), 0.f);
    o0.z = fmaxf(fmaf(acc[2], inv, s0.z), 0.f);
    o0.w = fmaxf(fmaf(acc[3], inv, s0.w), 0.f);
    o1.x = fmaxf(fmaf(acc[4], inv, s1.x), 0.f);
    o1.y = fmaxf(fmaf(acc[5], inv, s1.y), 0.f);
    o1.z = fmaxf(fmaf(acc[6], inv, s1.z), 0.f);
    o1.w = fmaxf(fmaf(acc[7], inv, s1.w), 0.f);
    float* op = out + (size_t)i * 64 + lane * 8;
    *(float4*)&op[0] = o0;
    *(float4*)&op[4] = o1;
}

extern "C" void kernel_launch(void* const* d_in, const int* in_sizes, int n_in,
                              void* d_out, int out_size, void* d_ws, size_t ws_size,
                              hipStream_t stream)
{
    const float* features = (const float*)d_in[0];
    const float* W1       = (const float*)d_in[1];
    const float* W2       = (const float*)d_in[2];
    const float* W3       = (const float*)d_in[3];
    const float* W4       = (const float*)d_in[4];
    const int*   nodes    = (const int*)d_in[5];
    const int*   neigh    = (const int*)d_in[6];
    float*       out      = (float*)d_out;

    unsigned short* B1h = (unsigned short*)d_ws;       // 65536
    unsigned short* B1l = B1h + 65536;
    unsigned short* B2h = B1l + 65536;                 // 32768
    unsigned short* B2l = B2h + 32768;
    unsigned short* B3h = B2l + 32768;
    unsigned short* B3l = B3h + 32768;
    unsigned short* B4h = B3l + 32768;                 // 16384
    unsigned short* B4l = B4h + 16384;
    float* gs = (float*)(B4l + 16384);                 // N*128 fp32, in-place L1-L3
    unsigned short* gnA = (unsigned short*)(gs + (size_t)N_NODES * 128); // N*128 bf16
    unsigned short* gnB = gnA + (size_t)N_NODES * 128; // N*128 bf16
    float* gs4 = (float*)gnB;                          // aliases gnB (free at L4)
    unsigned short* gn4 = gnB + (size_t)N_NODES * 128; // N*64 bf16

    prep_all<<<576, 256, 0, stream>>>(W1, W2, W3, W4,
                                      B1h, B1l, B2h, B2l, B3h, B3l, B4h, B4l);

    const int grid64 = (N_NODES + 63) / 64;   // 1563
    const int grid32 = (N_NODES + 31) / 32;   // 3125

    gemm1<<<grid64, 256, 0, stream>>>(features, B1h, B1l, gs, gnA, N_NODES);
    fused_layer<256><<<grid32, 256, 0, stream>>>(gs, gnA, neigh, B2h, B2l, gs, gnB, N_NODES);
    fused_layer<256><<<grid32, 256, 0, stream>>>(gs, gnB, neigh, B3h, B3l, gs, gnA, N_NODES);
    fused_layer<128><<<grid32, 256, 0, stream>>>(gs, gnA, neigh, B4h, B4l, gs4, gn4, N_NODES);
    agg_out<<<(N_NODES + 31) / 32, 256, 0, stream>>>(gs4, gn4, neigh, nodes, out, N_NODES);
}